// Round 4
// baseline (480.493 us; speedup 1.0000x reference)
//
#include <hip/hip_runtime.h>

// ExpansionContrastModule on MI355X (gfx950), bf16 MFMA pipeline.
// G1/G2 (the two K=2048 GEMMs) use a 256x256 8-wave deep-pipelined kernel:
// 4-slot LDS ring at K-half granularity, counted s_waitcnt vmcnt(8) (never
// drained to 0 in the loop), raw s_barrier, setprio around MFMA clusters.
// R4 fix: 64B-row LDS tiles get XOR swizzle slot ^= (row>>2)&3 on the read
// side, matched by pre-swizzled per-lane global source (k-chunk (l&3)^(l>>4))
// on the global_load_lds side -> restores the proven 2-way (free) bank
// pattern (r1/r2 measured 0 conflicts; r3's unswizzled 64B rows hit 12.6M).
// Remaining GEMMs use the verified 2-phase global_load_lds kernel.

typedef unsigned short u16;
typedef unsigned int u32;
typedef __attribute__((ext_vector_type(4))) unsigned int u32x4;
typedef __attribute__((ext_vector_type(8))) short s16x8;
typedef __attribute__((ext_vector_type(4))) float f32x4;

#define DEVFN static __device__ __forceinline__

DEVFN u16 f2bf(float f) {
    u32 u = __builtin_bit_cast(u32, f);
    u32 r = (u + 0x7fffu + ((u >> 16) & 1u)) >> 16;  // RNE
    return (u16)r;
}
DEVFN float bf2f(u32 h) { u32 u = h << 16; return __builtin_bit_cast(float, u); }

typedef __attribute__((address_space(1))) const unsigned int gu32;
typedef __attribute__((address_space(3))) unsigned int lu32;
DEVFN void gld16(const void* g, void* l) {
    __builtin_amdgcn_global_load_lds((gu32*)g, (lu32*)l, 16, 0, 0);
}

#define VMCNT8 do { asm volatile("s_waitcnt vmcnt(8)" ::: "memory"); \
                    __builtin_amdgcn_sched_barrier(0); } while (0)

// OFFSETS = [(-1,-1),(-1,0),(-1,1),(0,1),(1,1),(1,0),(1,-1),(0,-1)]
__constant__ int cOFFY[8] = {-1,-1,-1, 0, 1, 1, 1, 0};
__constant__ int cOFFX[8] = {-1, 0, 1, 1, 1, 0,-1,-1};

// ---------------------------------------------------------------------------
// 8-phase deep-pipelined 256x256 TN GEMM (T2+T3+T4+T5).
// D[M][N] = X[M][K] · Y[N][K]^T, bf16 in/out, f32 acc.
// 512 threads = 8 waves (2M x 4N); per-wave C = 128x64 (acc[8][4] f32x4).
// LDS ring: per operand 4 slots of [256 rows][32 k] (64B rows, 16 KiB).
// Slot of K-half (tile v, kstep ks) = (2v+ks) & 3. Per K-tile u, 4 phases:
//  P1: read A(u,k0) m0-7 + B(u,k0) n0-1 | stage A(u+1,k1) | bar | MFMA | bar
//  P2: read B(u,k0) n2-3               | stage B(u+1,k1) | bar | MFMA | VMCNT8 bar
//  P3: read A(u,k1) m0-7 + B(u,k1) n0-1| stage A(u+2,k0) | bar | MFMA | bar
//  P4: read B(u,k1) n2-3               | stage B(u+2,k0) | bar | MFMA | VMCNT8 bar
// Ledger: prologue = 12 loads; each phase issues 2; VMCNT8 at P2/P4 confirms
// exactly the half-tiles the next two phases read (verified r3, correct).
// LDS swizzle: 16B slot s of row r holds k-chunk s ^ ((r>>2)&3).
// ---------------------------------------------------------------------------
template<int XG, int YG, int NRM>
__global__ __launch_bounds__(512, 2)
void gemm8p(const u16* __restrict__ X, const u16* __restrict__ Y,
            u16* __restrict__ D, const u16* __restrict__ cenT,
            const char* __restrict__ zeroPg, float* __restrict__ nrm,
            int K, int ldx, int ldy, int ldd,
            long xb, long xs, long yb, long ys, long db, long dsn,
            long nb, long ns)
{
    const int tid  = threadIdx.x;
    const int lane = tid & 63;
    const int w    = tid >> 6;      // wave 0..7
    const int wm   = w >> 2;        // 0..1  (M half)
    const int wn   = w & 3;         // 0..3  (N quarter)
    const int z = blockIdx.z, b = z >> 2, s = z & 3;
    const int m0 = blockIdx.x * 256, n0 = blockIdx.y * 256;
    const int dil = s + 1;
    const int nt = K / 64;

    __shared__ __align__(16) char lds[147456];
    char* ldsA  = lds;              // 4 x 16 KiB
    char* ldsB  = lds + 65536;      // 4 x 16 KiB
    char* scrap = lds + 131072;     // 16 KiB dummy target for tail stages

    const char* cenB = (const char*)(cenT + (long)b * (4096 * 256));
    const char* Xb = nullptr; const char* Yb = nullptr;
    const long ldxB = (long)ldx * 2, ldyB = (long)ldy * 2;
    if constexpr (!XG) Xb = (const char*)(X + b * xb + (long)s * xs + (long)m0 * ldx);
    if constexpr (!YG) Yb = (const char*)(Y + b * yb + (long)s * ys + (long)n0 * ldy);

    // per-lane source k-chunk pre-swizzle (rule #21): LDS dest is linear
    // (lane -> row base+lane>>2, slot lane&3); slot s of row r must hold
    // k-chunk s ^ ((r>>2)&3) = (lane&3) ^ (lane>>4).
    const int kc = ((lane & 3) ^ (lane >> 4)) << 4;

    // stage one K-half (16 KiB): 2 gld16/thread. LDS dest wave-uniform.
    auto stageX = [&](int v, int ks) {
        #pragma unroll
        for (int i = 0; i < 2; i++) {
            const bool live = v < nt;
            const int vv = live ? v : 0;
            char* dst = (live ? ldsA + (((v + v + ks) & 3) << 14) : scrap)
                        + (w << 10) + (i << 13);
            if constexpr (!XG) {
                gld16(Xb + (long)(w * 16 + i * 128 + (lane >> 2)) * ldxB
                          + vv * 128 + ks * 64 + kc, dst);
            } else {
                const int j = vv >> 2;
                const int dy = cOFFY[j] * dil, dx = cOFFX[j] * dil;
                const int a = m0 + w * 16 + i * 128 + (lane >> 2);
                const int yy = (a >> 6) + dy, xx = (a & 63) + dx;
                const char* src = (((unsigned)yy < 64u) && ((unsigned)xx < 64u))
                    ? cenB + ((long)((yy << 6) + xx) << 9)
                           + ((vv & 3) * 128 + ks * 64 + kc)
                    : zeroPg + kc;
                gld16(src, dst);
            }
        }
    };
    auto stageY = [&](int v, int ks) {
        #pragma unroll
        for (int i = 0; i < 2; i++) {
            const bool live = v < nt;
            const int vv = live ? v : 0;
            char* dst = (live ? ldsB + (((v + v + ks) & 3) << 14) : scrap)
                        + (w << 10) + (i << 13);
            if constexpr (!YG) {
                gld16(Yb + (long)(w * 16 + i * 128 + (lane >> 2)) * ldyB
                          + vv * 128 + ks * 64 + kc, dst);
            } else {
                const int j = vv >> 2;
                const int dy = cOFFY[j] * dil, dx = cOFFX[j] * dil;
                const int a = n0 + w * 16 + i * 128 + (lane >> 2);
                const int yy = (a >> 6) + dy, xx = (a & 63) + dx;
                const char* src = (((unsigned)yy < 64u) && ((unsigned)xx < 64u))
                    ? cenB + ((long)((yy << 6) + xx) << 9)
                           + ((vv & 3) * 128 + ks * 64 + kc)
                    : zeroPg + kc;
                gld16(src, dst);
            }
        }
    };

    const int frow = lane & 15;
    // read-side swizzle: fk ^ ((row>>2)&3)<<4; (row>>2)&3 == (lane>>2)&3
    const int fk = (((lane >> 4) ^ ((lane >> 2) & 3)) << 4);
    auto ldA = [&](int slot, int m) -> s16x8 {
        return *(const s16x8*)(ldsA + (slot << 14) + (wm * 128 + m * 16 + frow) * 64 + fk);
    };
    auto ldB = [&](int slot, int n) -> s16x8 {
        return *(const s16x8*)(ldsB + (slot << 14) + (wn * 64 + n * 16 + frow) * 64 + fk);
    };

    f32x4 acc[8][4] = {};

    // prologue: 6 half-tiles = 12 loads/wave
    stageX(0, 0); stageY(0, 0);
    stageX(0, 1); stageY(0, 1);
    stageX(1, 0); stageY(1, 0);
    VMCNT8;                               // oldest 4 (A0k0,B0k0) landed
    __builtin_amdgcn_s_barrier();

    for (int u = 0; u < nt; u++) {
        const int s0 = (u + u) & 3, s1 = (u + u + 1) & 3;
        s16x8 af[8];
        // ---- P1: ks0, n0-1
        #pragma unroll
        for (int m = 0; m < 8; m++) af[m] = ldA(s0, m);
        { s16x8 b0v = ldB(s0, 0), b1v = ldB(s0, 1);
          stageX(u + 1, 1);
          __builtin_amdgcn_s_barrier();
          __builtin_amdgcn_s_setprio(1);
          #pragma unroll
          for (int m = 0; m < 8; m++) {
              acc[m][0] = __builtin_amdgcn_mfma_f32_16x16x32_bf16(af[m], b0v, acc[m][0], 0, 0, 0);
              acc[m][1] = __builtin_amdgcn_mfma_f32_16x16x32_bf16(af[m], b1v, acc[m][1], 0, 0, 0);
          }
          __builtin_amdgcn_s_setprio(0);
          __builtin_amdgcn_s_barrier(); }
        // ---- P2: ks0, n2-3
        { s16x8 b2v = ldB(s0, 2), b3v = ldB(s0, 3);
          stageY(u + 1, 1);
          __builtin_amdgcn_s_barrier();
          __builtin_amdgcn_s_setprio(1);
          #pragma unroll
          for (int m = 0; m < 8; m++) {
              acc[m][2] = __builtin_amdgcn_mfma_f32_16x16x32_bf16(af[m], b2v, acc[m][2], 0, 0, 0);
              acc[m][3] = __builtin_amdgcn_mfma_f32_16x16x32_bf16(af[m], b3v, acc[m][3], 0, 0, 0);
          }
          __builtin_amdgcn_s_setprio(0);
          VMCNT8;                         // publishes A(u,k1),B(u,k1)
          __builtin_amdgcn_s_barrier(); }
        // ---- P3: ks1, n0-1
        #pragma unroll
        for (int m = 0; m < 8; m++) af[m] = ldA(s1, m);
        { s16x8 b0v = ldB(s1, 0), b1v = ldB(s1, 1);
          stageX(u + 2, 0);
          __builtin_amdgcn_s_barrier();
          __builtin_amdgcn_s_setprio(1);
          #pragma unroll
          for (int m = 0; m < 8; m++) {
              acc[m][0] = __builtin_amdgcn_mfma_f32_16x16x32_bf16(af[m], b0v, acc[m][0], 0, 0, 0);
              acc[m][1] = __builtin_amdgcn_mfma_f32_16x16x32_bf16(af[m], b1v, acc[m][1], 0, 0, 0);
          }
          __builtin_amdgcn_s_setprio(0);
          __builtin_amdgcn_s_barrier(); }
        // ---- P4: ks1, n2-3
        { s16x8 b2v = ldB(s1, 2), b3v = ldB(s1, 3);
          stageY(u + 2, 0);
          __builtin_amdgcn_s_barrier();
          __builtin_amdgcn_s_setprio(1);
          #pragma unroll
          for (int m = 0; m < 8; m++) {
              acc[m][2] = __builtin_amdgcn_mfma_f32_16x16x32_bf16(af[m], b2v, acc[m][2], 0, 0, 0);
              acc[m][3] = __builtin_amdgcn_mfma_f32_16x16x32_bf16(af[m], b3v, acc[m][3], 0, 0, 0);
          }
          __builtin_amdgcn_s_setprio(0);
          VMCNT8;                         // publishes A(u+1,k0),B(u+1,k0)
          __builtin_amdgcn_s_barrier(); }
    }

    // ||row||^2 accumulation (bf16-rounded, = what the score GEMM consumes)
    if constexpr (NRM) {
        float* nrmP = nrm + b * nb + s * ns;
        #pragma unroll
        for (int m = 0; m < 8; m++) {
            float ss[4] = {0.f, 0.f, 0.f, 0.f};
            #pragma unroll
            for (int n = 0; n < 4; n++)
                #pragma unroll
                for (int i = 0; i < 4; i++) {
                    float v = bf2f(f2bf(acc[m][n][i]));
                    ss[i] += v * v;
                }
            #pragma unroll
            for (int o = 1; o < 16; o <<= 1)
                #pragma unroll
                for (int i = 0; i < 4; i++) ss[i] += __shfl_xor(ss[i], o);
            if ((lane & 15) == 0) {
                const int row0 = m0 + wm * 128 + m * 16 + ((lane >> 4) << 2);
                #pragma unroll
                for (int i = 0; i < 4; i++) atomicAdd(&nrmP[row0 + i], ss[i]);
            }
        }
    }

    // C-write: row = (lane>>4)*4 + i, col = lane&15
    u16* Dp = D + b * db + (long)s * dsn;
    #pragma unroll
    for (int m = 0; m < 8; m++) {
        const int row0 = m0 + wm * 128 + m * 16 + ((lane >> 4) << 2);
        #pragma unroll
        for (int n = 0; n < 4; n++) {
            const int col = n0 + wn * 64 + n * 16 + (lane & 15);
            #pragma unroll
            for (int i = 0; i < 4; i++)
                Dp[(long)(row0 + i) * ldd + col] = f2bf(acc[m][n][i]);
        }
    }
}

// ---------------------------------------------------------------------------
// 2-phase TN GEMM (verified rounds 1-2) — used for G3..G7.
// ---------------------------------------------------------------------------
DEVFN int swz(int r, int kb) { return r * 128 + (kb ^ ((r & 7) << 4)); }

template<int BM, int BN, int WRM, int WRN, int XG, int YG, int DM, int NRM, int SCL>
__global__ __launch_bounds__(256, 2)
void gemm_tn(const u16* __restrict__ X, const u16* __restrict__ Y,
             void* __restrict__ D, const u16* __restrict__ cenT,
             const char* __restrict__ zeroPg, float* __restrict__ nrm,
             const float* __restrict__ nQ, const float* __restrict__ nK,
             int K, int ldx, int ldy, int ldd, int sbits,
             long xb, long xs, long yb, long ys, long db, long dsn,
             long nb, long ns)
{
    const int tid  = threadIdx.x;
    const int lane = tid & 63;
    const int wid  = tid >> 6;
    const int z = blockIdx.z;
    const int b = z >> sbits;
    const int s = z & ((1 << sbits) - 1);
    const int m0 = blockIdx.x * BM;
    const int n0 = blockIdx.y * BN;
    const int dil = s + 1;
    const int wm0 = (wid >> 1) * (WRM * 16);
    const int wn0 = (wid & 1) * (WRN * 16);

    __shared__ __align__(16) char lds[2 * (BM + BN) * 128];

    const char* cenB = (const char*)(cenT + (long)b * (4096 * 256));
    const char* Xb = nullptr;
    const char* Yb = nullptr;
    if constexpr (!XG) Xb = (const char*)(X + b * xb + (long)s * xs + (long)m0 * ldx);
    if constexpr (!YG) Yb = (const char*)(Y + b * yb + (long)s * ys + (long)n0 * ldy);

    auto stage = [&](int bf, int t) {
        char* LX = lds + bf * ((BM + BN) * 128);
        char* LY = LX + BM * 128;
        if constexpr (!XG) {
            const char* base = Xb + (long)t * 128;
            #pragma unroll
            for (int r = 0; r < BM / 32; r++) {
                const int R = r * 32 + wid * 8 + (lane >> 3);
                gld16(base + (long)R * (ldx * 2) + (((lane & 7) * 16) ^ ((R & 7) << 4)),
                      LX + (r * 32 + wid * 8) * 128);
            }
        } else {
            const int j = t >> 2;
            const int dy = cOFFY[j] * dil, dx = cOFFX[j] * dil;
            const int cb = (t & 3) * 128;
            #pragma unroll
            for (int r = 0; r < BM / 32; r++) {
                const int R = r * 32 + wid * 8 + (lane >> 3);
                const int a = m0 + R, yy = (a >> 6) + dy, xx = (a & 63) + dx;
                const int off = ((lane & 7) * 16) ^ ((R & 7) << 4);
                const char* src = (((unsigned)yy < 64u) && ((unsigned)xx < 64u))
                    ? cenB + ((long)((yy << 6) + xx) << 9) + cb + off
                    : zeroPg + off;
                gld16(src, LX + (r * 32 + wid * 8) * 128);
            }
        }
        if constexpr (!YG) {
            const char* base = Yb + (long)t * 128;
            #pragma unroll
            for (int r = 0; r < BN / 32; r++) {
                const int R = r * 32 + wid * 8 + (lane >> 3);
                gld16(base + (long)R * (ldy * 2) + (((lane & 7) * 16) ^ ((R & 7) << 4)),
                      LY + (r * 32 + wid * 8) * 128);
            }
        } else {
            const int j = t >> 2;
            const int dy = cOFFY[j] * dil, dx = cOFFX[j] * dil;
            const int cb = (t & 3) * 128;
            #pragma unroll
            for (int r = 0; r < BN / 32; r++) {
                const int R = r * 32 + wid * 8 + (lane >> 3);
                const int a = n0 + R, yy = (a >> 6) + dy, xx = (a & 63) + dx;
                const int off = ((lane & 7) * 16) ^ ((R & 7) << 4);
                const char* src = (((unsigned)yy < 64u) && ((unsigned)xx < 64u))
                    ? cenB + ((long)((yy << 6) + xx) << 9) + cb + off
                    : zeroPg + off;
                gld16(src, LY + (r * 32 + wid * 8) * 128);
            }
        }
    };

    f32x4 acc[WRM][WRN] = {};

    auto comp = [&](int bf) {
        const char* LX = lds + bf * ((BM + BN) * 128);
        const char* LY = LX + BM * 128;
        #pragma unroll
        for (int kk = 0; kk < 2; kk++) {
            const int kb = kk * 64 + ((lane >> 4) << 4);
            s16x8 af[WRM], bfr[WRN];
            #pragma unroll
            for (int m = 0; m < WRM; m++)
                af[m] = *(const s16x8*)(LX + swz(wm0 + m * 16 + (lane & 15), kb));
            #pragma unroll
            for (int n = 0; n < WRN; n++)
                bfr[n] = *(const s16x8*)(LY + swz(wn0 + n * 16 + (lane & 15), kb));
            #pragma unroll
            for (int m = 0; m < WRM; m++)
                #pragma unroll
                for (int n = 0; n < WRN; n++)
                    acc[m][n] = __builtin_amdgcn_mfma_f32_16x16x32_bf16(af[m], bfr[n], acc[m][n], 0, 0, 0);
        }
    };

    const int nt = K / 64;
    stage(0, 0);
    __syncthreads();
    int cur = 0;
    for (int t = 0; t < nt; t++) {
        if (t + 1 < nt) stage(cur ^ 1, t + 1);
        comp(cur);
        __syncthreads();
        cur ^= 1;
    }

    if constexpr (NRM) {
        float* nrmP = nrm + b * nb + s * ns;
        #pragma unroll
        for (int m = 0; m < WRM; m++) {
            float ss[4] = {0.f, 0.f, 0.f, 0.f};
            #pragma unroll
            for (int n = 0; n < WRN; n++)
                #pragma unroll
                for (int i = 0; i < 4; i++) {
                    float v = bf2f(f2bf(acc[m][n][i]));
                    ss[i] += v * v;
                }
            #pragma unroll
            for (int o = 1; o < 16; o <<= 1)
                #pragma unroll
                for (int i = 0; i < 4; i++) ss[i] += __shfl_xor(ss[i], o);
            if ((lane & 15) == 0) {
                const int row0 = m0 + wm0 + m * 16 + ((lane >> 4) << 2);
                #pragma unroll
                for (int i = 0; i < 4; i++) atomicAdd(&nrmP[row0 + i], ss[i]);
            }
        }
    }

    const float* nQp = nullptr; const float* nKp = nullptr;
    if constexpr (SCL) { nQp = nQ + b * 256 + s * 64; nKp = nK + (b * 4 + s) * 512; }
    #pragma unroll
    for (int m = 0; m < WRM; m++) {
        const int row0 = m0 + wm0 + m * 16 + ((lane >> 4) << 2);
        #pragma unroll
        for (int n = 0; n < WRN; n++) {
            const int col = n0 + wn0 + n * 16 + (lane & 15);
            f32x4 a = acc[m][n];
            if constexpr (SCL) {
                const float sk = fmaxf(sqrtf(nKp[col]), 1e-12f);
                #pragma unroll
                for (int i = 0; i < 4; i++) {
                    const float sq = fmaxf(sqrtf(nQp[row0 + i]), 1e-12f);
                    a[i] *= 1.f / (sq * sk);
                }
            }
            if constexpr (DM == 1) {
                float* Dp = (float*)D + b * db + (long)s * dsn;
                #pragma unroll
                for (int i = 0; i < 4; i++) Dp[(long)(row0 + i) * ldd + col] = a[i];
            } else if constexpr (DM == 0) {
                u16* Dp = (u16*)D + b * db + (long)s * dsn;
                #pragma unroll
                for (int i = 0; i < 4; i++) Dp[(long)(row0 + i) * ldd + col] = f2bf(a[i]);
            } else {
                u16* Dp = (u16*)D;
                const int s2 = col >> 6, k2 = col & 63;
                const long base = (long)(b * 4 + s2) * 4096;
                #pragma unroll
                for (int i = 0; i < 4; i++)
                    Dp[(base + row0 + i) * 576 + 512 + k2] = f2bf(a[i]);
            }
        }
    }
}

// ---------------------------------------------------------------------------
// small kernels
// ---------------------------------------------------------------------------
__global__ __launch_bounds__(256) void zero_f32(float* __restrict__ p, int n) {
    int i = blockIdx.x * 256 + threadIdx.x;
    if (i < n) p[i] = 0.f;
}

__global__ void castbf(const float* __restrict__ src, u16* __restrict__ dst, int n8, float scale) {
    int i = blockIdx.x * 256 + threadIdx.x;
    if (i >= n8) return;
    const float* s = src + (long)i * 8;
    u32x4 o;
    #pragma unroll
    for (int j = 0; j < 4; j++) {
        u16 lo = f2bf(s[2 * j] * scale), hi = f2bf(s[2 * j + 1] * scale);
        o[j] = (u32)lo | ((u32)hi << 16);
    }
    *(u32x4*)(dst + (long)i * 8) = o;
}

// cen [b][256][4096] f32 -> cen_t [b][4096][256] bf16
__global__ __launch_bounds__(256) void transpose_cen(const float* __restrict__ cen, u16* __restrict__ cenT) {
    __shared__ float t[64][65];
    const int tx = threadIdx.x & 63, ty = threadIdx.x >> 6;
    const int a0 = blockIdx.x * 64, c0 = blockIdx.y * 64, b = blockIdx.z;
    const float* src = cen + ((long)(b * 256 + c0)) * 4096 + a0;
    #pragma unroll
    for (int i = 0; i < 16; i++) t[ty + i * 4][tx] = src[(long)(ty + i * 4) * 4096 + tx];
    __syncthreads();
    u16* dst = cenT + ((long)b * 4096 + a0) * 256 + c0;
    #pragma unroll
    for (int i = 0; i < 16; i++) dst[(long)(ty + i * 4) * 256 + tx] = f2bf(t[tx][ty + i * 4]);
}

// per (b,s): instance-norm over [64][512] f32 score, row softmax,
// write ws bf16 -> WSWC[...][0:512], wc (sum of 8 chunks) -> [512:576]
__global__ __launch_bounds__(256) void softmax_in(const float* __restrict__ score, u16* __restrict__ wswc) {
    const int bs = blockIdx.x, tid = threadIdx.x;
    const float* S = score + (long)bs * 32768;
    float s1 = 0.f, s2 = 0.f;
    for (int i = tid; i < 32768; i += 256) { float v = S[i]; s1 += v; s2 += v * v; }
    __shared__ float ra[256], rb[256];
    ra[tid] = s1; rb[tid] = s2; __syncthreads();
    for (int st = 128; st > 0; st >>= 1) {
        if (tid < st) { ra[tid] += ra[tid + st]; rb[tid] += rb[tid + st]; }
        __syncthreads();
    }
    const float mu = ra[0] * (1.f / 32768.f);
    const float var = rb[0] * (1.f / 32768.f) - mu * mu;
    const float rstd = rsqrtf(var + 1e-5f);
    const int wid = tid >> 6, lane = tid & 63;
    u16* W = wswc + (long)bs * 64 * 576;
    for (int r = wid; r < 64; r += 4) {
        float zv[8]; float mx = -3.0e38f;
        #pragma unroll
        for (int i = 0; i < 8; i++) { zv[i] = (S[r * 512 + i * 64 + lane] - mu) * rstd; mx = fmaxf(mx, zv[i]); }
        #pragma unroll
        for (int o = 32; o > 0; o >>= 1) mx = fmaxf(mx, __shfl_xor(mx, o));
        float sum = 0.f;
        #pragma unroll
        for (int i = 0; i < 8; i++) { zv[i] = __expf(zv[i] - mx); sum += zv[i]; }
        #pragma unroll
        for (int o = 32; o > 0; o >>= 1) sum += __shfl_xor(sum, o);
        const float inv = 1.f / sum;
        float wcv = 0.f;
        #pragma unroll
        for (int i = 0; i < 8; i++) {
            float w = zv[i] * inv; wcv += w;
            W[r * 576 + i * 64 + lane] = f2bf(w);
        }
        W[r * 576 + 512 + lane] = f2bf(wcv);
    }
}

// BN stats: per channel over (b=4, a=4096)
__global__ __launch_bounds__(256) void bn_stats(const float* __restrict__ out2, float* __restrict__ st) {
    const int c = blockIdx.x, tid = threadIdx.x;
    float s1 = 0.f, s2 = 0.f;
    for (int i = tid; i < 16384; i += 256) {
        const int b = i >> 12, a = i & 4095;
        float v = out2[((long)(b * 256 + c)) * 4096 + a];
        s1 += v; s2 += v * v;
    }
    __shared__ float ra[256], rb[256];
    ra[tid] = s1; rb[tid] = s2; __syncthreads();
    for (int stp = 128; stp > 0; stp >>= 1) {
        if (tid < stp) { ra[tid] += ra[tid + stp]; rb[tid] += rb[tid + stp]; }
        __syncthreads();
    }
    if (tid == 0) {
        float mu = ra[0] * (1.f / 16384.f);
        float var = rb[0] * (1.f / 16384.f) - mu * mu;
        st[c * 2] = mu;
        st[c * 2 + 1] = rsqrtf(var + 1e-5f);
    }
}

__global__ __launch_bounds__(256) void bn_apply(const float* __restrict__ out2, const float* __restrict__ st,
                                                const float* __restrict__ gamma, const float* __restrict__ beta,
                                                float* __restrict__ out) {
    const long i4 = (long)blockIdx.x * 256 + threadIdx.x;
    const f32x4 v = *(const f32x4*)(out2 + i4 * 4);
    const int c = (int)((i4 * 4) >> 12) & 255;
    const float g = gamma[c] * st[c * 2 + 1];
    const float bt = beta[c] - st[c * 2] * g;
    f32x4 o;
    #pragma unroll
    for (int j = 0; j < 4; j++) o[j] = fmaxf(v[j] * g + bt, 0.f);
    *(f32x4*)(out + i4 * 4) = o;
}

// ---------------------------------------------------------------------------
extern "C" void kernel_launch(void* const* d_in, const int* in_sizes, int n_in,
                              void* d_out, int out_size, void* d_ws, size_t ws_size,
                              hipStream_t stream) {
    (void)in_sizes; (void)n_in; (void)out_size; (void)ws_size;
    const float* cen   = (const float*)d_in[0];
    const float* qw    = (const float*)d_in[1];
    const float* lw    = (const float*)d_in[2];
    const float* kw    = (const float*)d_in[3];
    const float* vw    = (const float*)d_in[4];
    const float* ow    = (const float*)d_in[5];
    const float* gamma = (const float*)d_in[6];
    const float* beta  = (const float*)d_in[7];
    float* out = (float*)d_out;

    char* ws = (char*)d_ws;
    size_t off = 0;
    auto alloc = [&](size_t bytes) { size_t o = off; off += (bytes + 255) & ~(size_t)255; return o; };
    u16*   KWb   = (u16*)(ws + alloc(4L * 512 * 2048 * 2));
    u16*   VWb   = (u16*)(ws + alloc(4L * 512 * 2048 * 2));
    u16*   QWb   = (u16*)(ws + alloc(256L * 256 * 2));
    u16*   LWnb  = (u16*)(ws + alloc(256L * 256 * 2));
    u16*   OWb   = (u16*)(ws + alloc(256L * 256 * 2));
    u16*   cenT  = (u16*)(ws + alloc(4L * 4096 * 256 * 2));
    u16*   keys  = (u16*)(ws + alloc(16L * 512 * 4096 * 2));
    u16*   qs    = (u16*)(ws + alloc(16L * 64 * 4096 * 2));
    u16*   VLt   = (u16*)(ws + alloc(16L * 4096 * 576 * 2));
    float* score = (float*)(ws + alloc(16L * 64 * 512 * 4));
    u16*   WSWC  = (u16*)(ws + alloc(16L * 64 * 576 * 2));
    u16*   out1t = (u16*)(ws + alloc(4L * 4096 * 256 * 2));
    float* out2  = (float*)(ws + alloc(4L * 256 * 4096 * 4));
    float* bnst  = (float*)(ws + alloc(256L * 2 * 4));
    float* nrmB  = (float*)(ws + alloc((64L + 8192 + 1024) * 4));
    char*  zpg = (char*)nrmB;          // 256B zero page
    float* nK  = nrmB + 64;            // [b][s][512] ||key row||^2
    float* nQ  = nrmB + 64 + 8192;     // [b][256]    ||q row||^2

    // prep
    zero_f32<<<dim3(37), 256, 0, stream>>>(nrmB, 9280);
    castbf<<<dim3(2048), 256, 0, stream>>>(kw, KWb, 524288, 1.f);
    castbf<<<dim3(2048), 256, 0, stream>>>(vw, VWb, 524288, 1.f);
    castbf<<<dim3(32),   256, 0, stream>>>(qw, QWb, 8192, 1.f);
    castbf<<<dim3(32),   256, 0, stream>>>(lw, LWnb, 8192, -1.f);
    castbf<<<dim3(32),   256, 0, stream>>>(ow, OWb, 8192, 1.f);
    transpose_cen<<<dim3(64, 4, 4), 256, 0, stream>>>(cen, cenT);

    // G1 keys[bs][512][4096] = KW[s] · surr_t(b,s)^T  (Y gathered) + key norms
    gemm8p<0,1,1><<<dim3(2, 16, 16), 512, 0, stream>>>(
        KWb, nullptr, keys, cenT, zpg, nK,
        2048, 2048, 0, 4096,
        0L, 512L * 2048, 0L, 0L, 4L * 512 * 4096, 512L * 4096, 2048L, 512L);
    // G2 vals_t into VLt[...][0:512] = surr_t(b,s) · VW[s]^T  (X gathered)
    gemm8p<1,0,0><<<dim3(16, 2, 16), 512, 0, stream>>>(
        nullptr, VWb, VLt, cenT, zpg, nullptr,
        2048, 0, 2048, 576,
        0L, 0L, 0L, 512L * 2048, 4L * 4096 * 576, 4096L * 576, 0L, 0L);
    // G3 qs[b][256][4096] = QW_all · cen_t[b]^T  + q norms
    gemm_tn<128,128,4,4, 0,0, 0, 1,0><<<dim3(2, 32, 4), 256, 0, stream>>>(
        QWb, cenT, qs, cenT, zpg, nQ, nullptr, nullptr,
        256, 256, 256, 4096, 0,
        0L, 0L, 4096L * 256, 0L, 256L * 4096, 0L, 256L, 0L);
    // G4 -locs_t scattered into VLt[...][512:576] = cen_t[b] · (-LW_all)^T
    gemm_tn<128,128,4,4, 0,0, 2, 0,0><<<dim3(32, 2, 4), 256, 0, stream>>>(
        cenT, LWnb, VLt, cenT, zpg, nullptr, nullptr, nullptr,
        256, 256, 256, 0, 0,
        4096L * 256, 0L, 0L, 0L, 0L, 0L, 0L, 0L);

    // G5 score[bs][64][512] = (q·k^T) / (|q||k|)  (f32 out, SCL epilogue)
    gemm_tn<64,64,2,2, 0,0, 1, 0,1><<<dim3(1, 8, 16), 256, 0, stream>>>(
        qs, keys, score, cenT, zpg, nullptr, nQ, nK,
        4096, 4096, 4096, 512, 2,
        256L * 4096, 64L * 4096, 4L * 512 * 4096, 512L * 4096, 4L * 64 * 512, 64L * 512, 0L, 0L);

    softmax_in<<<dim3(16), 256, 0, stream>>>(score, WSWC);

    // G6 out1_t[b][4096][s*64+h] = VLt[bs] · WSWC[bs]^T  (K=576)
    gemm_tn<128,64,4,2, 0,0, 0, 0,0><<<dim3(32, 1, 16), 256, 0, stream>>>(
        VLt, WSWC, out1t, cenT, zpg, nullptr, nullptr, nullptr,
        576, 576, 576, 256, 2,
        4L * 4096 * 576, 4096L * 576, 4L * 64 * 576, 64L * 576, 4096L * 256, 64L, 0L, 0L);
    // G7 out2[b][256][4096] = OW · out1_t[b]^T  (f32 out)
    gemm_tn<128,128,4,4, 0,0, 1, 0,0><<<dim3(2, 32, 4), 256, 0, stream>>>(
        OWb, out1t, out2, cenT, zpg, nullptr, nullptr, nullptr,
        256, 256, 256, 4096, 0,
        0L, 0L, 4096L * 256, 0L, 256L * 4096, 0L, 0L, 0L);

    bn_stats<<<dim3(256), 256, 0, stream>>>(out2, bnst);
    bn_apply<<<dim3(4096), 256, 0, stream>>>(out2, bnst, gamma, beta, out);
}

// Round 5
// 460.619 us; speedup vs baseline: 1.0431x; 1.0431x over previous
//
#include <hip/hip_runtime.h>

// ExpansionContrastModule on MI355X (gfx950), bf16 MFMA pipeline.
// G1 (K=2048 GEMM) uses the 256x256 8-wave deep-pipelined kernel (gemm8p):
// 4-slot LDS ring at K-half granularity, counted s_waitcnt vmcnt(8), raw
// s_barrier, setprio around MFMA clusters.
// R5 conflict fix: 64B-row LDS slot function sigma(r,c) = c ^ ((r>>1)&3)
// so every 8 consecutive lanes cover all eight 16B positions of the 128B
// bank stripe exactly once (the signature of the measured-zero gemm_tn
// pattern). Source pre-swizzle kc = (l&3)^((l>>3)&3) matches (rule #21).
// G2 is HEDGED back to the proven 2-phase gemm_tn (in-run A/B control).

typedef unsigned short u16;
typedef unsigned int u32;
typedef __attribute__((ext_vector_type(4))) unsigned int u32x4;
typedef __attribute__((ext_vector_type(8))) short s16x8;
typedef __attribute__((ext_vector_type(4))) float f32x4;

#define DEVFN static __device__ __forceinline__

DEVFN u16 f2bf(float f) {
    u32 u = __builtin_bit_cast(u32, f);
    u32 r = (u + 0x7fffu + ((u >> 16) & 1u)) >> 16;  // RNE
    return (u16)r;
}
DEVFN float bf2f(u32 h) { u32 u = h << 16; return __builtin_bit_cast(float, u); }

typedef __attribute__((address_space(1))) const unsigned int gu32;
typedef __attribute__((address_space(3))) unsigned int lu32;
DEVFN void gld16(const void* g, void* l) {
    __builtin_amdgcn_global_load_lds((gu32*)g, (lu32*)l, 16, 0, 0);
}

#define VMCNT8 do { asm volatile("s_waitcnt vmcnt(8)" ::: "memory"); \
                    __builtin_amdgcn_sched_barrier(0); } while (0)

// OFFSETS = [(-1,-1),(-1,0),(-1,1),(0,1),(1,1),(1,0),(1,-1),(0,-1)]
__constant__ int cOFFY[8] = {-1,-1,-1, 0, 1, 1, 1, 0};
__constant__ int cOFFX[8] = {-1, 0, 1, 1, 1, 0,-1,-1};

// ---------------------------------------------------------------------------
// 8-phase deep-pipelined 256x256 TN GEMM (T2+T3+T4+T5).
// D[M][N] = X[M][K] · Y[N][K]^T, bf16 in/out, f32 acc.
// 512 threads = 8 waves (2M x 4N); per-wave C = 128x64 (acc[8][4] f32x4).
// LDS ring: per operand 4 slots of [256 rows][32 k] (64B rows, 16 KiB).
// Slot of K-half (tile v, kstep ks) = (2v+ks) & 3. Per K-tile u, 4 phases:
//  P1: read A(u,k0) m0-7 + B(u,k0) n0-1 | stage A(u+1,k1) | bar | MFMA | bar
//  P2: read B(u,k0) n2-3               | stage B(u+1,k1) | bar | MFMA | VMCNT8 bar
//  P3: read A(u,k1) m0-7 + B(u,k1) n0-1| stage A(u+2,k0) | bar | MFMA | bar
//  P4: read B(u,k1) n2-3               | stage B(u+2,k0) | bar | MFMA | VMCNT8 bar
// Ledger: prologue = 12 loads; each phase issues 2; VMCNT8 at P2/P4 confirms
// exactly the half-tiles the next two phases read.
// LDS bank map: 16B slot s of row r holds k-chunk s ^ ((r>>1)&3).
// ---------------------------------------------------------------------------
template<int XG, int YG, int NRM>
__global__ __launch_bounds__(512, 2)
void gemm8p(const u16* __restrict__ X, const u16* __restrict__ Y,
            u16* __restrict__ D, const u16* __restrict__ cenT,
            const char* __restrict__ zeroPg, float* __restrict__ nrm,
            int K, int ldx, int ldy, int ldd,
            long xb, long xs, long yb, long ys, long db, long dsn,
            long nb, long ns)
{
    const int tid  = threadIdx.x;
    const int lane = tid & 63;
    const int w    = tid >> 6;      // wave 0..7
    const int wm   = w >> 2;        // 0..1  (M half)
    const int wn   = w & 3;         // 0..3  (N quarter)
    const int z = blockIdx.z, b = z >> 2, s = z & 3;
    const int m0 = blockIdx.x * 256, n0 = blockIdx.y * 256;
    const int dil = s + 1;
    const int nt = K / 64;

    __shared__ __align__(16) char lds[147456];
    char* ldsA  = lds;              // 4 x 16 KiB
    char* ldsB  = lds + 65536;      // 4 x 16 KiB
    char* scrap = lds + 131072;     // 16 KiB dummy target for tail stages

    const char* cenB = (const char*)(cenT + (long)b * (4096 * 256));
    const char* Xb = nullptr; const char* Yb = nullptr;
    const long ldxB = (long)ldx * 2, ldyB = (long)ldy * 2;
    if constexpr (!XG) Xb = (const char*)(X + b * xb + (long)s * xs + (long)m0 * ldx);
    if constexpr (!YG) Yb = (const char*)(Y + b * yb + (long)s * ys + (long)n0 * ldy);

    // per-lane source k-chunk pre-swizzle (rule #21): LDS dest is linear
    // (lane -> row base+(l>>2), slot l&3); slot s of row r must hold
    // k-chunk s ^ ((r>>1)&3); (r>>1)&3 of lane l's row = (l>>3)&3.
    const int kc = (((lane & 3) ^ ((lane >> 3) & 3)) << 4);

    // stage one K-half (16 KiB): 2 gld16/thread. LDS dest wave-uniform.
    auto stageX = [&](int v, int ks) {
        #pragma unroll
        for (int i = 0; i < 2; i++) {
            const bool live = v < nt;
            const int vv = live ? v : 0;
            char* dst = (live ? ldsA + (((v + v + ks) & 3) << 14) : scrap)
                        + (w << 10) + (i << 13);
            if constexpr (!XG) {
                gld16(Xb + (long)(w * 16 + i * 128 + (lane >> 2)) * ldxB
                          + vv * 128 + ks * 64 + kc, dst);
            } else {
                const int j = vv >> 2;
                const int dy = cOFFY[j] * dil, dx = cOFFX[j] * dil;
                const int a = m0 + w * 16 + i * 128 + (lane >> 2);
                const int yy = (a >> 6) + dy, xx = (a & 63) + dx;
                const char* src = (((unsigned)yy < 64u) && ((unsigned)xx < 64u))
                    ? cenB + ((long)((yy << 6) + xx) << 9)
                           + ((vv & 3) * 128 + ks * 64 + kc)
                    : zeroPg + kc;
                gld16(src, dst);
            }
        }
    };
    auto stageY = [&](int v, int ks) {
        #pragma unroll
        for (int i = 0; i < 2; i++) {
            const bool live = v < nt;
            const int vv = live ? v : 0;
            char* dst = (live ? ldsB + (((v + v + ks) & 3) << 14) : scrap)
                        + (w << 10) + (i << 13);
            if constexpr (!YG) {
                gld16(Yb + (long)(w * 16 + i * 128 + (lane >> 2)) * ldyB
                          + vv * 128 + ks * 64 + kc, dst);
            } else {
                const int j = vv >> 2;
                const int dy = cOFFY[j] * dil, dx = cOFFX[j] * dil;
                const int a = n0 + w * 16 + i * 128 + (lane >> 2);
                const int yy = (a >> 6) + dy, xx = (a & 63) + dx;
                const char* src = (((unsigned)yy < 64u) && ((unsigned)xx < 64u))
                    ? cenB + ((long)((yy << 6) + xx) << 9)
                           + ((vv & 3) * 128 + ks * 64 + kc)
                    : zeroPg + kc;
                gld16(src, dst);
            }
        }
    };

    const int frow = lane & 15;
    // read-side slot: c ^ ((r>>1)&3) with c = lane>>4, (r>>1)&3 = (lane>>1)&3.
    // -> lanes 0..7 hit positions 0,64,16,80,32,96,48,112 (all 8 distinct).
    const int fk = (((lane >> 4) ^ ((lane >> 1) & 3)) << 4);
    auto ldA = [&](int slot, int m) -> s16x8 {
        return *(const s16x8*)(ldsA + (slot << 14) + (wm * 128 + m * 16 + frow) * 64 + fk);
    };
    auto ldB = [&](int slot, int n) -> s16x8 {
        return *(const s16x8*)(ldsB + (slot << 14) + (wn * 64 + n * 16 + frow) * 64 + fk);
    };

    f32x4 acc[8][4] = {};

    // prologue: 6 half-tiles = 12 loads/wave
    stageX(0, 0); stageY(0, 0);
    stageX(0, 1); stageY(0, 1);
    stageX(1, 0); stageY(1, 0);
    VMCNT8;                               // oldest 4 (A0k0,B0k0) landed
    __builtin_amdgcn_s_barrier();

    for (int u = 0; u < nt; u++) {
        const int s0 = (u + u) & 3, s1 = (u + u + 1) & 3;
        s16x8 af[8];
        // ---- P1: ks0, n0-1
        #pragma unroll
        for (int m = 0; m < 8; m++) af[m] = ldA(s0, m);
        { s16x8 b0v = ldB(s0, 0), b1v = ldB(s0, 1);
          stageX(u + 1, 1);
          __builtin_amdgcn_s_barrier();
          __builtin_amdgcn_s_setprio(1);
          #pragma unroll
          for (int m = 0; m < 8; m++) {
              acc[m][0] = __builtin_amdgcn_mfma_f32_16x16x32_bf16(af[m], b0v, acc[m][0], 0, 0, 0);
              acc[m][1] = __builtin_amdgcn_mfma_f32_16x16x32_bf16(af[m], b1v, acc[m][1], 0, 0, 0);
          }
          __builtin_amdgcn_s_setprio(0);
          __builtin_amdgcn_s_barrier(); }
        // ---- P2: ks0, n2-3
        { s16x8 b2v = ldB(s0, 2), b3v = ldB(s0, 3);
          stageY(u + 1, 1);
          __builtin_amdgcn_s_barrier();
          __builtin_amdgcn_s_setprio(1);
          #pragma unroll
          for (int m = 0; m < 8; m++) {
              acc[m][2] = __builtin_amdgcn_mfma_f32_16x16x32_bf16(af[m], b2v, acc[m][2], 0, 0, 0);
              acc[m][3] = __builtin_amdgcn_mfma_f32_16x16x32_bf16(af[m], b3v, acc[m][3], 0, 0, 0);
          }
          __builtin_amdgcn_s_setprio(0);
          VMCNT8;                         // publishes A(u,k1),B(u,k1)
          __builtin_amdgcn_s_barrier(); }
        // ---- P3: ks1, n0-1
        #pragma unroll
        for (int m = 0; m < 8; m++) af[m] = ldA(s1, m);
        { s16x8 b0v = ldB(s1, 0), b1v = ldB(s1, 1);
          stageX(u + 2, 0);
          __builtin_amdgcn_s_barrier();
          __builtin_amdgcn_s_setprio(1);
          #pragma unroll
          for (int m = 0; m < 8; m++) {
              acc[m][0] = __builtin_amdgcn_mfma_f32_16x16x32_bf16(af[m], b0v, acc[m][0], 0, 0, 0);
              acc[m][1] = __builtin_amdgcn_mfma_f32_16x16x32_bf16(af[m], b1v, acc[m][1], 0, 0, 0);
          }
          __builtin_amdgcn_s_setprio(0);
          __builtin_amdgcn_s_barrier(); }
        // ---- P4: ks1, n2-3
        { s16x8 b2v = ldB(s1, 2), b3v = ldB(s1, 3);
          stageY(u + 2, 0);
          __builtin_amdgcn_s_barrier();
          __builtin_amdgcn_s_setprio(1);
          #pragma unroll
          for (int m = 0; m < 8; m++) {
              acc[m][2] = __builtin_amdgcn_mfma_f32_16x16x32_bf16(af[m], b2v, acc[m][2], 0, 0, 0);
              acc[m][3] = __builtin_amdgcn_mfma_f32_16x16x32_bf16(af[m], b3v, acc[m][3], 0, 0, 0);
          }
          __builtin_amdgcn_s_setprio(0);
          VMCNT8;                         // publishes A(u+1,k0),B(u+1,k0)
          __builtin_amdgcn_s_barrier(); }
    }

    // ||row||^2 accumulation (bf16-rounded, = what the score GEMM consumes)
    if constexpr (NRM) {
        float* nrmP = nrm + b * nb + s * ns;
        #pragma unroll
        for (int m = 0; m < 8; m++) {
            float ss[4] = {0.f, 0.f, 0.f, 0.f};
            #pragma unroll
            for (int n = 0; n < 4; n++)
                #pragma unroll
                for (int i = 0; i < 4; i++) {
                    float v = bf2f(f2bf(acc[m][n][i]));
                    ss[i] += v * v;
                }
            #pragma unroll
            for (int o = 1; o < 16; o <<= 1)
                #pragma unroll
                for (int i = 0; i < 4; i++) ss[i] += __shfl_xor(ss[i], o);
            if ((lane & 15) == 0) {
                const int row0 = m0 + wm * 128 + m * 16 + ((lane >> 4) << 2);
                #pragma unroll
                for (int i = 0; i < 4; i++) atomicAdd(&nrmP[row0 + i], ss[i]);
            }
        }
    }

    // C-write: row = (lane>>4)*4 + i, col = lane&15
    u16* Dp = D + b * db + (long)s * dsn;
    #pragma unroll
    for (int m = 0; m < 8; m++) {
        const int row0 = m0 + wm * 128 + m * 16 + ((lane >> 4) << 2);
        #pragma unroll
        for (int n = 0; n < 4; n++) {
            const int col = n0 + wn * 64 + n * 16 + (lane & 15);
            #pragma unroll
            for (int i = 0; i < 4; i++)
                Dp[(long)(row0 + i) * ldd + col] = f2bf(acc[m][n][i]);
        }
    }
}

// ---------------------------------------------------------------------------
// 2-phase TN GEMM (verified rounds 1-2) — used for G2..G7.
// ---------------------------------------------------------------------------
DEVFN int swz(int r, int kb) { return r * 128 + (kb ^ ((r & 7) << 4)); }

template<int BM, int BN, int WRM, int WRN, int XG, int YG, int DM, int NRM, int SCL>
__global__ __launch_bounds__(256, 2)
void gemm_tn(const u16* __restrict__ X, const u16* __restrict__ Y,
             void* __restrict__ D, const u16* __restrict__ cenT,
             const char* __restrict__ zeroPg, float* __restrict__ nrm,
             const float* __restrict__ nQ, const float* __restrict__ nK,
             int K, int ldx, int ldy, int ldd, int sbits,
             long xb, long xs, long yb, long ys, long db, long dsn,
             long nb, long ns)
{
    const int tid  = threadIdx.x;
    const int lane = tid & 63;
    const int wid  = tid >> 6;
    const int z = blockIdx.z;
    const int b = z >> sbits;
    const int s = z & ((1 << sbits) - 1);
    const int m0 = blockIdx.x * BM;
    const int n0 = blockIdx.y * BN;
    const int dil = s + 1;
    const int wm0 = (wid >> 1) * (WRM * 16);
    const int wn0 = (wid & 1) * (WRN * 16);

    __shared__ __align__(16) char lds[2 * (BM + BN) * 128];

    const char* cenB = (const char*)(cenT + (long)b * (4096 * 256));
    const char* Xb = nullptr;
    const char* Yb = nullptr;
    if constexpr (!XG) Xb = (const char*)(X + b * xb + (long)s * xs + (long)m0 * ldx);
    if constexpr (!YG) Yb = (const char*)(Y + b * yb + (long)s * ys + (long)n0 * ldy);

    auto stage = [&](int bf, int t) {
        char* LX = lds + bf * ((BM + BN) * 128);
        char* LY = LX + BM * 128;
        if constexpr (!XG) {
            const char* base = Xb + (long)t * 128;
            #pragma unroll
            for (int r = 0; r < BM / 32; r++) {
                const int R = r * 32 + wid * 8 + (lane >> 3);
                gld16(base + (long)R * (ldx * 2) + (((lane & 7) * 16) ^ ((R & 7) << 4)),
                      LX + (r * 32 + wid * 8) * 128);
            }
        } else {
            const int j = t >> 2;
            const int dy = cOFFY[j] * dil, dx = cOFFX[j] * dil;
            const int cb = (t & 3) * 128;
            #pragma unroll
            for (int r = 0; r < BM / 32; r++) {
                const int R = r * 32 + wid * 8 + (lane >> 3);
                const int a = m0 + R, yy = (a >> 6) + dy, xx = (a & 63) + dx;
                const int off = ((lane & 7) * 16) ^ ((R & 7) << 4);
                const char* src = (((unsigned)yy < 64u) && ((unsigned)xx < 64u))
                    ? cenB + ((long)((yy << 6) + xx) << 9) + cb + off
                    : zeroPg + off;
                gld16(src, LX + (r * 32 + wid * 8) * 128);
            }
        }
        if constexpr (!YG) {
            const char* base = Yb + (long)t * 128;
            #pragma unroll
            for (int r = 0; r < BN / 32; r++) {
                const int R = r * 32 + wid * 8 + (lane >> 3);
                gld16(base + (long)R * (ldy * 2) + (((lane & 7) * 16) ^ ((R & 7) << 4)),
                      LY + (r * 32 + wid * 8) * 128);
            }
        } else {
            const int j = t >> 2;
            const int dy = cOFFY[j] * dil, dx = cOFFX[j] * dil;
            const int cb = (t & 3) * 128;
            #pragma unroll
            for (int r = 0; r < BN / 32; r++) {
                const int R = r * 32 + wid * 8 + (lane >> 3);
                const int a = n0 + R, yy = (a >> 6) + dy, xx = (a & 63) + dx;
                const int off = ((lane & 7) * 16) ^ ((R & 7) << 4);
                const char* src = (((unsigned)yy < 64u) && ((unsigned)xx < 64u))
                    ? cenB + ((long)((yy << 6) + xx) << 9) + cb + off
                    : zeroPg + off;
                gld16(src, LY + (r * 32 + wid * 8) * 128);
            }
        }
    };

    f32x4 acc[WRM][WRN] = {};

    auto comp = [&](int bf) {
        const char* LX = lds + bf * ((BM + BN) * 128);
        const char* LY = LX + BM * 128;
        #pragma unroll
        for (int kk = 0; kk < 2; kk++) {
            const int kb = kk * 64 + ((lane >> 4) << 4);
            s16x8 af[WRM], bfr[WRN];
            #pragma unroll
            for (int m = 0; m < WRM; m++)
                af[m] = *(const s16x8*)(LX + swz(wm0 + m * 16 + (lane & 15), kb));
            #pragma unroll
            for (int n = 0; n < WRN; n++)
                bfr[n] = *(const s16x8*)(LY + swz(wn0 + n * 16 + (lane & 15), kb));
            #pragma unroll
            for (int m = 0; m < WRM; m++)
                #pragma unroll
                for (int n = 0; n < WRN; n++)
                    acc[m][n] = __builtin_amdgcn_mfma_f32_16x16x32_bf16(af[m], bfr[n], acc[m][n], 0, 0, 0);
        }
    };

    const int nt = K / 64;
    stage(0, 0);
    __syncthreads();
    int cur = 0;
    for (int t = 0; t < nt; t++) {
        if (t + 1 < nt) stage(cur ^ 1, t + 1);
        comp(cur);
        __syncthreads();
        cur ^= 1;
    }

    if constexpr (NRM) {
        float* nrmP = nrm + b * nb + s * ns;
        #pragma unroll
        for (int m = 0; m < WRM; m++) {
            float ss[4] = {0.f, 0.f, 0.f, 0.f};
            #pragma unroll
            for (int n = 0; n < WRN; n++)
                #pragma unroll
                for (int i = 0; i < 4; i++) {
                    float v = bf2f(f2bf(acc[m][n][i]));
                    ss[i] += v * v;
                }
            #pragma unroll
            for (int o = 1; o < 16; o <<= 1)
                #pragma unroll
                for (int i = 0; i < 4; i++) ss[i] += __shfl_xor(ss[i], o);
            if ((lane & 15) == 0) {
                const int row0 = m0 + wm0 + m * 16 + ((lane >> 4) << 2);
                #pragma unroll
                for (int i = 0; i < 4; i++) atomicAdd(&nrmP[row0 + i], ss[i]);
            }
        }
    }

    const float* nQp = nullptr; const float* nKp = nullptr;
    if constexpr (SCL) { nQp = nQ + b * 256 + s * 64; nKp = nK + (b * 4 + s) * 512; }
    #pragma unroll
    for (int m = 0; m < WRM; m++) {
        const int row0 = m0 + wm0 + m * 16 + ((lane >> 4) << 2);
        #pragma unroll
        for (int n = 0; n < WRN; n++) {
            const int col = n0 + wn0 + n * 16 + (lane & 15);
            f32x4 a = acc[m][n];
            if constexpr (SCL) {
                const float sk = fmaxf(sqrtf(nKp[col]), 1e-12f);
                #pragma unroll
                for (int i = 0; i < 4; i++) {
                    const float sq = fmaxf(sqrtf(nQp[row0 + i]), 1e-12f);
                    a[i] *= 1.f / (sq * sk);
                }
            }
            if constexpr (DM == 1) {
                float* Dp = (float*)D + b * db + (long)s * dsn;
                #pragma unroll
                for (int i = 0; i < 4; i++) Dp[(long)(row0 + i) * ldd + col] = a[i];
            } else if constexpr (DM == 0) {
                u16* Dp = (u16*)D + b * db + (long)s * dsn;
                #pragma unroll
                for (int i = 0; i < 4; i++) Dp[(long)(row0 + i) * ldd + col] = f2bf(a[i]);
            } else {
                u16* Dp = (u16*)D;
                const int s2 = col >> 6, k2 = col & 63;
                const long base = (long)(b * 4 + s2) * 4096;
                #pragma unroll
                for (int i = 0; i < 4; i++)
                    Dp[(base + row0 + i) * 576 + 512 + k2] = f2bf(a[i]);
            }
        }
    }
}

// ---------------------------------------------------------------------------
// small kernels
// ---------------------------------------------------------------------------
__global__ __launch_bounds__(256) void zero_f32(float* __restrict__ p, int n) {
    int i = blockIdx.x * 256 + threadIdx.x;
    if (i < n) p[i] = 0.f;
}

__global__ void castbf(const float* __restrict__ src, u16* __restrict__ dst, int n8, float scale) {
    int i = blockIdx.x * 256 + threadIdx.x;
    if (i >= n8) return;
    const float* s = src + (long)i * 8;
    u32x4 o;
    #pragma unroll
    for (int j = 0; j < 4; j++) {
        u16 lo = f2bf(s[2 * j] * scale), hi = f2bf(s[2 * j + 1] * scale);
        o[j] = (u32)lo | ((u32)hi << 16);
    }
    *(u32x4*)(dst + (long)i * 8) = o;
}

// cen [b][256][4096] f32 -> cen_t [b][4096][256] bf16
__global__ __launch_bounds__(256) void transpose_cen(const float* __restrict__ cen, u16* __restrict__ cenT) {
    __shared__ float t[64][65];
    const int tx = threadIdx.x & 63, ty = threadIdx.x >> 6;
    const int a0 = blockIdx.x * 64, c0 = blockIdx.y * 64, b = blockIdx.z;
    const float* src = cen + ((long)(b * 256 + c0)) * 4096 + a0;
    #pragma unroll
    for (int i = 0; i < 16; i++) t[ty + i * 4][tx] = src[(long)(ty + i * 4) * 4096 + tx];
    __syncthreads();
    u16* dst = cenT + ((long)b * 4096 + a0) * 256 + c0;
    #pragma unroll
    for (int i = 0; i < 16; i++) dst[(long)(ty + i * 4) * 256 + tx] = f2bf(t[tx][ty + i * 4]);
}

// per (b,s): instance-norm over [64][512] f32 score, row softmax,
// write ws bf16 -> WSWC[...][0:512], wc (sum of 8 chunks) -> [512:576]
__global__ __launch_bounds__(256) void softmax_in(const float* __restrict__ score, u16* __restrict__ wswc) {
    const int bs = blockIdx.x, tid = threadIdx.x;
    const float* S = score + (long)bs * 32768;
    float s1 = 0.f, s2 = 0.f;
    for (int i = tid; i < 32768; i += 256) { float v = S[i]; s1 += v; s2 += v * v; }
    __shared__ float ra[256], rb[256];
    ra[tid] = s1; rb[tid] = s2; __syncthreads();
    for (int st = 128; st > 0; st >>= 1) {
        if (tid < st) { ra[tid] += ra[tid + st]; rb[tid] += rb[tid + st]; }
        __syncthreads();
    }
    const float mu = ra[0] * (1.f / 32768.f);
    const float var = rb[0] * (1.f / 32768.f) - mu * mu;
    const float rstd = rsqrtf(var + 1e-5f);
    const int wid = tid >> 6, lane = tid & 63;
    u16* W = wswc + (long)bs * 64 * 576;
    for (int r = wid; r < 64; r += 4) {
        float zv[8]; float mx = -3.0e38f;
        #pragma unroll
        for (int i = 0; i < 8; i++) { zv[i] = (S[r * 512 + i * 64 + lane] - mu) * rstd; mx = fmaxf(mx, zv[i]); }
        #pragma unroll
        for (int o = 32; o > 0; o >>= 1) mx = fmaxf(mx, __shfl_xor(mx, o));
        float sum = 0.f;
        #pragma unroll
        for (int i = 0; i < 8; i++) { zv[i] = __expf(zv[i] - mx); sum += zv[i]; }
        #pragma unroll
        for (int o = 32; o > 0; o >>= 1) sum += __shfl_xor(sum, o);
        const float inv = 1.f / sum;
        float wcv = 0.f;
        #pragma unroll
        for (int i = 0; i < 8; i++) {
            float w = zv[i] * inv; wcv += w;
            W[r * 576 + i * 64 + lane] = f2bf(w);
        }
        W[r * 576 + 512 + lane] = f2bf(wcv);
    }
}

// BN stats: per channel over (b=4, a=4096)
__global__ __launch_bounds__(256) void bn_stats(const float* __restrict__ out2, float* __restrict__ st) {
    const int c = blockIdx.x, tid = threadIdx.x;
    float s1 = 0.f, s2 = 0.f;
    for (int i = tid; i < 16384; i += 256) {
        const int b = i >> 12, a = i & 4095;
        float v = out2[((long)(b * 256 + c)) * 4096 + a];
        s1 += v; s2 += v * v;
    }
    __shared__ float ra[256], rb[256];
    ra[tid] = s1; rb[tid] = s2; __syncthreads();
    for (int stp = 128; stp > 0; stp >>= 1) {
        if (tid < stp) { ra[tid] += ra[tid + stp]; rb[tid] += rb[tid + stp]; }
        __syncthreads();
    }
    if (tid == 0) {
        float mu = ra[0] * (1.f / 16384.f);
        float var = rb[0] * (1.f / 16384.f) - mu * mu;
        st[c * 2] = mu;
        st[c * 2 + 1] = rsqrtf(var + 1e-5f);
    }
}

__global__ __launch_bounds__(256) void bn_apply(const float* __restrict__ out2, const float* __restrict__ st,
                                                const float* __restrict__ gamma, const float* __restrict__ beta,
                                                float* __restrict__ out) {
    const long i4 = (long)blockIdx.x * 256 + threadIdx.x;
    const f32x4 v = *(const f32x4*)(out2 + i4 * 4);
    const int c = (int)((i4 * 4) >> 12) & 255;
    const float g = gamma[c] * st[c * 2 + 1];
    const float bt = beta[c] - st[c * 2] * g;
    f32x4 o;
    #pragma unroll
    for (int j = 0; j < 4; j++) o[j] = fmaxf(v[j] * g + bt, 0.f);
    *(f32x4*)(out + i4 * 4) = o;
}

// ---------------------------------------------------------------------------
extern "C" void kernel_launch(void* const* d_in, const int* in_sizes, int n_in,
                              void* d_out, int out_size, void* d_ws, size_t ws_size,
                              hipStream_t stream) {
    (void)in_sizes; (void)n_in; (void)out_size; (void)ws_size;
    const float* cen   = (const float*)d_in[0];
    const float* qw    = (const float*)d_in[1];
    const float* lw    = (const float*)d_in[2];
    const float* kw    = (const float*)d_in[3];
    const float* vw    = (const float*)d_in[4];
    const float* ow    = (const float*)d_in[5];
    const float* gamma = (const float*)d_in[6];
    const float* beta  = (const float*)d_in[7];
    float* out = (float*)d_out;

    char* ws = (char*)d_ws;
    size_t off = 0;
    auto alloc = [&](size_t bytes) { size_t o = off; off += (bytes + 255) & ~(size_t)255; return o; };
    u16*   KWb   = (u16*)(ws + alloc(4L * 512 * 2048 * 2));
    u16*   VWb   = (u16*)(ws + alloc(4L * 512 * 2048 * 2));
    u16*   QWb   = (u16*)(ws + alloc(256L * 256 * 2));
    u16*   LWnb  = (u16*)(ws + alloc(256L * 256 * 2));
    u16*   OWb   = (u16*)(ws + alloc(256L * 256 * 2));
    u16*   cenT  = (u16*)(ws + alloc(4L * 4096 * 256 * 2));
    u16*   keys  = (u16*)(ws + alloc(16L * 512 * 4096 * 2));
    u16*   qs    = (u16*)(ws + alloc(16L * 64 * 4096 * 2));
    u16*   VLt   = (u16*)(ws + alloc(16L * 4096 * 576 * 2));
    float* score = (float*)(ws + alloc(16L * 64 * 512 * 4));
    u16*   WSWC  = (u16*)(ws + alloc(16L * 64 * 576 * 2));
    u16*   out1t = (u16*)(ws + alloc(4L * 4096 * 256 * 2));
    float* out2  = (float*)(ws + alloc(4L * 256 * 4096 * 4));
    float* bnst  = (float*)(ws + alloc(256L * 2 * 4));
    float* nrmB  = (float*)(ws + alloc((64L + 8192 + 1024) * 4));
    char*  zpg = (char*)nrmB;          // 256B zero page
    float* nK  = nrmB + 64;            // [b][s][512] ||key row||^2
    float* nQ  = nrmB + 64 + 8192;     // [b][256]    ||q row||^2

    // prep
    zero_f32<<<dim3(37), 256, 0, stream>>>(nrmB, 9280);
    castbf<<<dim3(2048), 256, 0, stream>>>(kw, KWb, 524288, 1.f);
    castbf<<<dim3(2048), 256, 0, stream>>>(vw, VWb, 524288, 1.f);
    castbf<<<dim3(32),   256, 0, stream>>>(qw, QWb, 8192, 1.f);
    castbf<<<dim3(32),   256, 0, stream>>>(lw, LWnb, 8192, -1.f);
    castbf<<<dim3(32),   256, 0, stream>>>(ow, OWb, 8192, 1.f);
    transpose_cen<<<dim3(64, 4, 4), 256, 0, stream>>>(cen, cenT);

    // G1 keys[bs][512][4096] = KW[s] · surr_t(b,s)^T  (Y gathered) + key norms
    // (8-phase kernel with fixed bank map)
    gemm8p<0,1,1><<<dim3(2, 16, 16), 512, 0, stream>>>(
        KWb, nullptr, keys, cenT, zpg, nK,
        2048, 2048, 0, 4096,
        0L, 512L * 2048, 0L, 0L, 4L * 512 * 4096, 512L * 4096, 2048L, 512L);
    // G2 vals_t into VLt[...][0:512] = surr_t(b,s) · VW[s]^T  (X gathered)
    // (hedged back to the proven 2-phase kernel, in-run control)
    gemm_tn<128,128,4,4, 1,0, 0, 0,0><<<dim3(32, 4, 16), 256, 0, stream>>>(
        nullptr, VWb, VLt, cenT, zpg, nullptr, nullptr, nullptr,
        2048, 0, 2048, 576, 2,
        0L, 0L, 0L, 512L * 2048, 4L * 4096 * 576, 4096L * 576, 0L, 0L);
    // G3 qs[b][256][4096] = QW_all · cen_t[b]^T  + q norms
    gemm_tn<128,128,4,4, 0,0, 0, 1,0><<<dim3(2, 32, 4), 256, 0, stream>>>(
        QWb, cenT, qs, cenT, zpg, nQ, nullptr, nullptr,
        256, 256, 256, 4096, 0,
        0L, 0L, 4096L * 256, 0L, 256L * 4096, 0L, 256L, 0L);
    // G4 -locs_t scattered into VLt[...][512:576] = cen_t[b] · (-LW_all)^T
    gemm_tn<128,128,4,4, 0,0, 2, 0,0><<<dim3(32, 2, 4), 256, 0, stream>>>(
        cenT, LWnb, VLt, cenT, zpg, nullptr, nullptr, nullptr,
        256, 256, 256, 0, 0,
        4096L * 256, 0L, 0L, 0L, 0L, 0L, 0L, 0L);

    // G5 score[bs][64][512] = (q·k^T) / (|q||k|)  (f32 out, SCL epilogue)
    gemm_tn<64,64,2,2, 0,0, 1, 0,1><<<dim3(1, 8, 16), 256, 0, stream>>>(
        qs, keys, score, cenT, zpg, nullptr, nQ, nK,
        4096, 4096, 4096, 512, 2,
        256L * 4096, 64L * 4096, 4L * 512 * 4096, 512L * 4096, 4L * 64 * 512, 64L * 512, 0L, 0L);

    softmax_in<<<dim3(16), 256, 0, stream>>>(score, WSWC);

    // G6 out1_t[b][4096][s*64+h] = VLt[bs] · WSWC[bs]^T  (K=576)
    gemm_tn<128,64,4,2, 0,0, 0, 0,0><<<dim3(32, 1, 16), 256, 0, stream>>>(
        VLt, WSWC, out1t, cenT, zpg, nullptr, nullptr, nullptr,
        576, 576, 576, 256, 2,
        4L * 4096 * 576, 4096L * 576, 4L * 64 * 576, 64L * 576, 4096L * 256, 64L, 0L, 0L);
    // G7 out2[b][256][4096] = OW · out1_t[b]^T  (f32 out)
    gemm_tn<128,128,4,4, 0,0, 1, 0,0><<<dim3(2, 32, 4), 256, 0, stream>>>(
        OWb, out1t, out2, cenT, zpg, nullptr, nullptr, nullptr,
        256, 256, 256, 4096, 0,
        0L, 0L, 4096L * 256, 0L, 256L * 4096, 0L, 0L, 0L);

    bn_stats<<<dim3(256), 256, 0, stream>>>(out2, bnst);
    bn_apply<<<dim3(4096), 256, 0, stream>>>(out2, bnst, gamma, beta, out);
}